// Round 1
// baseline (585.359 us; speedup 1.0000x reference)
//
#include <hip/hip_runtime.h>
#include <hip/hip_bf16.h>
#include <math.h>

// Problem constants (from setup_inputs): B=1, I=J=256, C=128, H=4, CH=32
#define NI 256
#define NJ 256
#define NC 128
#define NH 4
#define NCH 32
#define TOK_PER_BLK 32

// ---------------------------------------------------------------------------
// Kernel 1: LayerNorm + projections q,k,v,g + tri bias.
// One block = 32 tokens. 256 threads.
//   q,k,v,g stored in [I, H, J, CH] layout (attention-friendly).
//   tri stored [H][a(=I idx)][b(=J idx)].
// q pre-scaled by CH^-0.5; g = sigmoid(xn@wg + bg).
// ---------------------------------------------------------------------------
__global__ __launch_bounds__(256) void ln_proj_kernel(
    const float* __restrict__ x, const float* __restrict__ ln_w, const float* __restrict__ ln_b,
    const float* __restrict__ w_tri, const float* __restrict__ wq, const float* __restrict__ wk,
    const float* __restrict__ wv, const float* __restrict__ wg, const float* __restrict__ bg,
    float* __restrict__ q, float* __restrict__ k, float* __restrict__ v, float* __restrict__ g,
    float* __restrict__ tri)
{
    __shared__ float xn[TOK_PER_BLK][NC];   // 16 KB
    const int tid = threadIdx.x;
    const long base = (long)blockIdx.x * TOK_PER_BLK * NC;

    // ---- LayerNorm: token t = tid/8, 8 lanes each handle 16 channels ----
    const int t = tid >> 3;
    const int lane8 = tid & 7;
    const float4* xrow = (const float4*)(x + base + (long)t * NC + lane8 * 16);
    float4 xv[4];
    float s = 0.f;
    #pragma unroll
    for (int u = 0; u < 4; ++u) {
        xv[u] = xrow[u];
        s += xv[u].x + xv[u].y + xv[u].z + xv[u].w;
    }
    #pragma unroll
    for (int off = 4; off; off >>= 1) s += __shfl_down(s, off, 8);
    const float mu = __shfl(s, 0, 8) * (1.f / (float)NC);
    float s2 = 0.f;
    #pragma unroll
    for (int u = 0; u < 4; ++u) {
        float dx = xv[u].x - mu; s2 += dx * dx;
        dx = xv[u].y - mu; s2 += dx * dx;
        dx = xv[u].z - mu; s2 += dx * dx;
        dx = xv[u].w - mu; s2 += dx * dx;
    }
    #pragma unroll
    for (int off = 4; off; off >>= 1) s2 += __shfl_down(s2, off, 8);
    const float rstd = rsqrtf(__shfl(s2, 0, 8) * (1.f / (float)NC) + 1e-5f);
    #pragma unroll
    for (int u = 0; u < 4; ++u) {
        const int c = lane8 * 16 + u * 4;
        float4 o4;
        o4.x = (xv[u].x - mu) * rstd * ln_w[c + 0] + ln_b[c + 0];
        o4.y = (xv[u].y - mu) * rstd * ln_w[c + 1] + ln_b[c + 1];
        o4.z = (xv[u].z - mu) * rstd * ln_w[c + 2] + ln_b[c + 2];
        o4.w = (xv[u].w - mu) * rstd * ln_w[c + 3] + ln_b[c + 3];
        *(float4*)&xn[t][c] = o4;
    }
    __syncthreads();

    // ---- Projections: thread col = tid%128, matrix pair = tid/128 ----
    const int col = tid & 127;
    const int m0 = tid >> 7;                 // wave-uniform (0 for tid<128, 1 else)
    const float* Wsel0 = (m0 == 0) ? wq : wk;
    const float* Wsel1 = (m0 == 0) ? wv : wg;
    const int h = col >> 5, ch = col & 31;

    #pragma unroll
    for (int p = 0; p < 2; ++p) {
        const int m = m0 + 2 * p;            // 0:q 1:k 2:v 3:g
        const float* W = (p == 0) ? Wsel0 : Wsel1;
        float acc[TOK_PER_BLK];
        #pragma unroll
        for (int t2 = 0; t2 < TOK_PER_BLK; ++t2) acc[t2] = 0.f;
        for (int c0 = 0; c0 < NC; c0 += 4) {
            const float w0 = W[(c0 + 0) * NC + col];
            const float w1 = W[(c0 + 1) * NC + col];
            const float w2 = W[(c0 + 2) * NC + col];
            const float w3 = W[(c0 + 3) * NC + col];
            #pragma unroll
            for (int t2 = 0; t2 < TOK_PER_BLK; ++t2) {
                const float4 a4 = *(const float4*)&xn[t2][c0];
                acc[t2] += a4.x * w0 + a4.y * w1 + a4.z * w2 + a4.w * w3;
            }
        }
        float* O = (m == 0) ? q : (m == 1) ? k : (m == 2) ? v : g;
        const float bgv = (m == 3) ? bg[col] : 0.f;
        #pragma unroll
        for (int t2 = 0; t2 < TOK_PER_BLK; ++t2) {
            const long gt = (long)blockIdx.x * TOK_PER_BLK + t2;
            const int i = (int)(gt >> 8), j = (int)(gt & 255);
            const long idx = ((((long)i * NH + h) * NJ) + j) * NCH + ch;
            float val = acc[t2];
            if (m == 0) val *= 0.17677669529663689f;             // CH^-0.5
            if (m == 3) val = 1.f / (1.f + __expf(-(val + bgv)));
            O[idx] = val;
        }
    }

    // ---- tri bias: 128 outputs per block (32 tokens x 4 heads) ----
    if (tid < 128) {
        const int th = tid & 3, tt = tid >> 2;
        float acc = 0.f;
        for (int c = 0; c < NC; ++c) acc += xn[tt][c] * w_tri[c * NH + th];
        const long gt = (long)blockIdx.x * TOK_PER_BLK + tt;
        const int i = (int)(gt >> 8), j = (int)(gt & 255);
        tri[((long)th * NI + i) * NJ + j] = acc;
    }
}

// ---------------------------------------------------------------------------
// Kernel 2: gated attention over J per (row i, head h). Flash-style online
// softmax, one query per thread. K,V staged in LDS (64 KB exactly).
// ---------------------------------------------------------------------------
__global__ __launch_bounds__(256) void attn_kernel(
    const float* __restrict__ q, const float* __restrict__ k, const float* __restrict__ v,
    const float* __restrict__ g, const float* __restrict__ tri, const float* __restrict__ mask,
    float* __restrict__ og)
{
    __shared__ float Ks[NJ][NCH];   // 32 KB
    __shared__ float Vs[NJ][NCH];   // 32 KB
    const int i = blockIdx.x;
    const int h = blockIdx.y;
    const int tid = threadIdx.x;    // = query index jq
    const long base = ((long)i * NH + h) * NJ * NCH;

    // cooperative load of K,V tiles (8192 floats each)
    {
        const float4* k4 = (const float4*)(k + base);
        const float4* v4 = (const float4*)(v + base);
        float4* K4 = (float4*)&Ks[0][0];
        float4* V4 = (float4*)&Vs[0][0];
        for (int u = tid; u < NJ * NCH / 4; u += 256) { K4[u] = k4[u]; V4[u] = v4[u]; }
    }
    __syncthreads();

    // per-thread query fragment
    float qr[NCH];
    {
        const float4* q4 = (const float4*)(q + base + (long)tid * NCH);
        #pragma unroll
        for (int u = 0; u < 8; ++u) {
            const float4 t4 = q4[u];
            qr[4*u] = t4.x; qr[4*u+1] = t4.y; qr[4*u+2] = t4.z; qr[4*u+3] = t4.w;
        }
    }
    const float* trirow = tri + ((long)h * NI + tid) * NJ;
    const float* maskrow = mask + (long)i * NJ;

    float mrun = -1e30f, l = 0.f;
    float o[NCH];
    #pragma unroll
    for (int u = 0; u < NCH; ++u) o[u] = 0.f;

    for (int jk0 = 0; jk0 < NJ; jk0 += 4) {
        const float4 tb = *(const float4*)(trirow + jk0);
        const float4 mk = *(const float4*)(maskrow + jk0);
        const float tbv[4] = {tb.x, tb.y, tb.z, tb.w};
        const float mbv[4] = {1.0e9f * (mk.x - 1.f), 1.0e9f * (mk.y - 1.f),
                              1.0e9f * (mk.z - 1.f), 1.0e9f * (mk.w - 1.f)};
        #pragma unroll
        for (int u = 0; u < 4; ++u) {
            const int jk = jk0 + u;
            float sc = tbv[u] + mbv[u];
            const float4* Kr = (const float4*)&Ks[jk][0];
            #pragma unroll
            for (int c = 0; c < 8; ++c) {
                const float4 kv = Kr[c];
                sc += qr[4*c] * kv.x + qr[4*c+1] * kv.y + qr[4*c+2] * kv.z + qr[4*c+3] * kv.w;
            }
            if (sc > mrun) {
                const float alpha = __expf(mrun - sc);
                l *= alpha;
                #pragma unroll
                for (int c = 0; c < NCH; ++c) o[c] *= alpha;
                mrun = sc;
            }
            const float p = __expf(sc - mrun);
            l += p;
            const float4* Vr = (const float4*)&Vs[jk][0];
            #pragma unroll
            for (int c = 0; c < 8; ++c) {
                const float4 vv = Vr[c];
                o[4*c]   += p * vv.x; o[4*c+1] += p * vv.y;
                o[4*c+2] += p * vv.z; o[4*c+3] += p * vv.w;
            }
        }
    }

    // epilogue: normalize, gate, write to [ (i*J + jq)*128 + h*32 + ch ]
    const float rl = 1.f / l;
    const float4* g4 = (const float4*)(g + base + (long)tid * NCH);
    float* outp = og + (((long)i * NJ + tid) * (NH * NCH)) + h * NCH;
    #pragma unroll
    for (int u = 0; u < 8; ++u) {
        const float4 gv = g4[u];
        float4 ov;
        ov.x = o[4*u]   * rl * gv.x;
        ov.y = o[4*u+1] * rl * gv.y;
        ov.z = o[4*u+2] * rl * gv.z;
        ov.w = o[4*u+3] * rl * gv.w;
        *(float4*)(outp + 4 * u) = ov;
    }
}

// ---------------------------------------------------------------------------
// Kernel 3: output projection [65536,128] @ wo[128,128] + bo.
// One block = 32 tokens, 256 threads (2 half-tiles of 16 tokens x 128 cols).
// ---------------------------------------------------------------------------
__global__ __launch_bounds__(256) void out_proj_kernel(
    const float* __restrict__ og, const float* __restrict__ wo, const float* __restrict__ bo,
    float* __restrict__ out)
{
    __shared__ float tile[TOK_PER_BLK][NC];  // 16 KB
    const int tid = threadIdx.x;
    const long base = (long)blockIdx.x * TOK_PER_BLK * NC;
    {
        const float4* src = (const float4*)(og + base);
        float4* dst4 = (float4*)&tile[0][0];
        for (int u = tid; u < TOK_PER_BLK * NC / 4; u += 256) dst4[u] = src[u];
    }
    __syncthreads();

    const int col = tid & 127;
    const int half = tid >> 7;
    float acc[16];
    #pragma unroll
    for (int t = 0; t < 16; ++t) acc[t] = 0.f;
    for (int c0 = 0; c0 < NC; c0 += 4) {
        const float w0 = wo[(c0 + 0) * NC + col];
        const float w1 = wo[(c0 + 1) * NC + col];
        const float w2 = wo[(c0 + 2) * NC + col];
        const float w3 = wo[(c0 + 3) * NC + col];
        #pragma unroll
        for (int t = 0; t < 16; ++t) {
            const float4 a4 = *(const float4*)&tile[half * 16 + t][c0];
            acc[t] += a4.x * w0 + a4.y * w1 + a4.z * w2 + a4.w * w3;
        }
    }
    const float b = bo[col];
    #pragma unroll
    for (int t = 0; t < 16; ++t)
        out[base + (long)(half * 16 + t) * NC + col] = acc[t] + b;
}

// ---------------------------------------------------------------------------
extern "C" void kernel_launch(void* const* d_in, const int* in_sizes, int n_in,
                              void* d_out, int out_size, void* d_ws, size_t ws_size,
                              hipStream_t stream) {
    const float* x     = (const float*)d_in[0];
    const float* mask  = (const float*)d_in[1];
    // d_in[2] = chunk_size (unused: chunk_size==0 path)
    const float* ln_w  = (const float*)d_in[3];
    const float* ln_b  = (const float*)d_in[4];
    const float* w_tri = (const float*)d_in[5];
    const float* wq    = (const float*)d_in[6];
    const float* wk    = (const float*)d_in[7];
    const float* wv    = (const float*)d_in[8];
    const float* wg    = (const float*)d_in[9];
    const float* bg    = (const float*)d_in[10];
    const float* wo    = (const float*)d_in[11];
    const float* bo    = (const float*)d_in[12];
    float* out = (float*)d_out;

    float* ws = (float*)d_ws;
    const long NTOK = (long)NI * NJ;           // 65536
    const long QSZ  = NTOK * NC;               // 8388608 floats per tensor
    float* q   = ws;
    float* k   = ws + QSZ;
    float* v   = ws + 2 * QSZ;
    float* g   = ws + 3 * QSZ;
    float* og  = ws + 4 * QSZ;
    float* tri = ws + 5 * QSZ;                 // H*I*J = 262144 floats

    hipLaunchKernelGGL(ln_proj_kernel, dim3(NTOK / TOK_PER_BLK), dim3(256), 0, stream,
                       x, ln_w, ln_b, w_tri, wq, wk, wv, wg, bg, q, k, v, g, tri);
    hipLaunchKernelGGL(attn_kernel, dim3(NI, NH), dim3(256), 0, stream,
                       q, k, v, g, tri, mask, og);
    hipLaunchKernelGGL(out_proj_kernel, dim3(NTOK / TOK_PER_BLK), dim3(256), 0, stream,
                       og, wo, bo, out);
}

// Round 2
// 192.912 us; speedup vs baseline: 3.0343x; 3.0343x over previous
//
#include <hip/hip_runtime.h>
#include <math.h>

// B=1, I=J=256, C=128, H=4, CH=32
#define NI 256
#define NJ 256
#define NC 128
#define NH 4
#define NCH 32

typedef __attribute__((ext_vector_type(8)))  __bf16        bf16x8;
typedef __attribute__((ext_vector_type(8)))  unsigned short u16x8;
typedef __attribute__((ext_vector_type(16))) float         f32x16;

__device__ __forceinline__ unsigned short f2bf(float f) {
    unsigned u = __builtin_bit_cast(unsigned, f);
    u += 0x7fffu + ((u >> 16) & 1u);          // RNE
    return (unsigned short)(u >> 16);
}
__device__ __forceinline__ float bf2f(unsigned short s) {
    return __builtin_bit_cast(float, ((unsigned)s) << 16);
}
__device__ __forceinline__ f32x16 fzero16() {
    f32x16 z;
#pragma unroll
    for (int r = 0; r < 16; ++r) z[r] = 0.f;
    return z;
}
__device__ __forceinline__ f32x16 mfma16(bf16x8 a, bf16x8 b, f32x16 c) {
    return __builtin_amdgcn_mfma_f32_32x32x16_bf16(a, b, c, 0, 0, 0);
}

// ---------------------------------------------------------------------------
// Kernel 0: transpose+convert weights to bf16.
// Wt_all[m*128+col][k] = W_m[k][col]  (m: 0=q,1=k,2=v,3=g), Wto[col][k] = wo[k][col]
// ---------------------------------------------------------------------------
__global__ __launch_bounds__(256) void convert_weights(
    const float* __restrict__ wq, const float* __restrict__ wk,
    const float* __restrict__ wv, const float* __restrict__ wg,
    const float* __restrict__ wo,
    unsigned short* __restrict__ Wt_all, unsigned short* __restrict__ Wto)
{
    int id = blockIdx.x * 256 + threadIdx.x;          // 0..81919
    if (id < 4 * 16384) {
        int m = id >> 14, r = id & 16383;
        int kk = r >> 7, c = r & 127;                 // reads coalesced over c
        const float* W = (m == 0) ? wq : (m == 1) ? wk : (m == 2) ? wv : wg;
        Wt_all[(m * 128 + c) * 128 + kk] = f2bf(W[kk * 128 + c]);
    } else {
        int r = id - 4 * 16384;
        int kk = r >> 7, c = r & 127;
        Wto[c * 128 + kk] = f2bf(wo[kk * 128 + c]);
    }
}

// ---------------------------------------------------------------------------
// Kernel 1: LayerNorm + MFMA projections (q,k,v,g) + tri bias.
// Block = 64 tokens, 256 threads (4 waves). Wave w computes h=w for all 4
// output matrices (ntile = w + 4*nt -> matrix nt, head w).
// q,k,v,g bf16 in [i][h][j][ch]; tri fp32 [h][a][b].
// ---------------------------------------------------------------------------
#define XNP 136   // padded LDS row stride (bf16 elements), 16B-aligned rows
__global__ __launch_bounds__(256, 2) void ln_proj_mfma(
    const float* __restrict__ x, const float* __restrict__ ln_w, const float* __restrict__ ln_b,
    const float* __restrict__ w_tri, const unsigned short* __restrict__ Wt_all,
    const float* __restrict__ bg,
    unsigned short* __restrict__ q, unsigned short* __restrict__ k,
    unsigned short* __restrict__ v, unsigned short* __restrict__ g,
    float* __restrict__ tri)
{
    __shared__ unsigned short xn[64 * XNP];   // ~17.4 KB
    __shared__ float wtri_s[NC * NH];         // 2 KB
    const int tid = threadIdx.x;
    const long tok0 = (long)blockIdx.x * 64;

    // stage w_tri (512 floats)
    ((float2*)wtri_s)[tid] = ((const float2*)w_tri)[tid];

    // ---- LayerNorm: 2 passes x 32 tokens; 8 lanes/token, 16 ch each ----
    const int lane8 = tid & 7;
#pragma unroll
    for (int p = 0; p < 2; ++p) {
        const int t = p * 32 + (tid >> 3);
        const float4* xrow = (const float4*)(x + (tok0 + t) * NC + lane8 * 16);
        float4 xv[4];
        float s = 0.f;
#pragma unroll
        for (int u = 0; u < 4; ++u) {
            xv[u] = xrow[u];
            s += xv[u].x + xv[u].y + xv[u].z + xv[u].w;
        }
#pragma unroll
        for (int off = 4; off; off >>= 1) s += __shfl_down(s, off, 8);
        const float mu = __shfl(s, 0, 8) * (1.f / (float)NC);
        float s2 = 0.f;
#pragma unroll
        for (int u = 0; u < 4; ++u) {
            float dx;
            dx = xv[u].x - mu; s2 += dx * dx;
            dx = xv[u].y - mu; s2 += dx * dx;
            dx = xv[u].z - mu; s2 += dx * dx;
            dx = xv[u].w - mu; s2 += dx * dx;
        }
#pragma unroll
        for (int off = 4; off; off >>= 1) s2 += __shfl_down(s2, off, 8);
        const float rstd = rsqrtf(__shfl(s2, 0, 8) * (1.f / (float)NC) + 1e-5f);
#pragma unroll
        for (int u = 0; u < 4; ++u) {
            const int c = lane8 * 16 + u * 4;
            const float4 lw = *(const float4*)(ln_w + c);
            const float4 lb = *(const float4*)(ln_b + c);
            float o0 = (xv[u].x - mu) * rstd * lw.x + lb.x;
            float o1 = (xv[u].y - mu) * rstd * lw.y + lb.y;
            float o2 = (xv[u].z - mu) * rstd * lw.z + lb.z;
            float o3 = (xv[u].w - mu) * rstd * lw.w + lb.w;
            unsigned p0 = (unsigned)f2bf(o0) | ((unsigned)f2bf(o1) << 16);
            unsigned p1 = (unsigned)f2bf(o2) | ((unsigned)f2bf(o3) << 16);
            *(unsigned*)&xn[t * XNP + c]     = p0;
            *(unsigned*)&xn[t * XNP + c + 2] = p1;
        }
    }
    __syncthreads();

    // ---- MFMA GEMM [64,128] @ [128,512] ----
    const int w = tid >> 6, L = tid & 63, lh = L >> 5, lc = L & 31;
    f32x16 acc[2][4];
#pragma unroll
    for (int mt = 0; mt < 2; ++mt)
#pragma unroll
        for (int nt = 0; nt < 4; ++nt) acc[mt][nt] = fzero16();

#pragma unroll
    for (int k0 = 0; k0 < 8; ++k0) {
        bf16x8 a0 = *(const bf16x8*)&xn[(lc)      * XNP + k0 * 16 + lh * 8];
        bf16x8 a1 = *(const bf16x8*)&xn[(32 + lc) * XNP + k0 * 16 + lh * 8];
#pragma unroll
        for (int nt = 0; nt < 4; ++nt) {
            const int ntile = w + 4 * nt;
            bf16x8 b = *(const bf16x8*)&Wt_all[(ntile * 32 + lc) * 128 + k0 * 16 + lh * 8];
            acc[0][nt] = mfma16(a0, b, acc[0][nt]);
            acc[1][nt] = mfma16(a1, b, acc[1][nt]);
        }
    }

    // ---- epilogue: scale(q) / sigmoid(g), store bf16 [i][h][j][ch] ----
    const float bgv = bg[w * 32 + lc];
#pragma unroll
    for (int mt = 0; mt < 2; ++mt) {
#pragma unroll
        for (int nt = 0; nt < 4; ++nt) {
            unsigned short* O = (nt == 0) ? q : (nt == 1) ? k : (nt == 2) ? v : g;
#pragma unroll
            for (int r = 0; r < 16; ++r) {
                const int row = mt * 32 + (r & 3) + 8 * (r >> 2) + 4 * lh;
                const long flat = tok0 + row;
                const int a = (int)(flat >> 8), b_ = (int)(flat & 255);
                float val = acc[mt][nt][r];
                if (nt == 0) val *= 0.17677669529663689f;        // CH^-0.5
                if (nt == 3) val = 1.f / (1.f + __expf(-(val + bgv)));
                O[(((long)a * NH + w) * NJ + b_) * NCH + lc] = f2bf(val);
            }
        }
    }

    // ---- tri bias: one (token, head) per thread, dot over 128 ch ----
    {
        const int tt = tid >> 2, th = tid & 3;
        float accT = 0.f;
#pragma unroll 8
        for (int c = 0; c < NC; c += 2) {
            const unsigned pr = *(const unsigned*)&xn[tt * XNP + c];
            accT += bf2f((unsigned short)pr)          * wtri_s[c * NH + th]
                  + bf2f((unsigned short)(pr >> 16))  * wtri_s[(c + 1) * NH + th];
        }
        const long flat = tok0 + tt;
        const int a = (int)(flat >> 8), b_ = (int)(flat & 255);
        tri[((long)th * NI + a) * NJ + b_] = accT;
    }
}

// ---------------------------------------------------------------------------
// Kernel 2: MFMA attention. Block=(i,h,qhalf), 256 threads, wave owns 32 q.
// Full-row softmax in registers (S = 32q x 256k per wave), P via LDS
// round-trip into A-operand layout, O = P@V with Vt in LDS.
// ---------------------------------------------------------------------------
#define KSP 40    // Ks row stride (elements)
#define VTP 264   // Vt row stride
#define PBP 40    // P buffer row stride
__global__ __launch_bounds__(256, 2) void attn_mfma(
    const unsigned short* __restrict__ q, const unsigned short* __restrict__ k,
    const unsigned short* __restrict__ v, const unsigned short* __restrict__ g,
    const float* __restrict__ tri, const float* __restrict__ mask,
    unsigned short* __restrict__ og)
{
    __shared__ unsigned short Ks[256 * KSP];      // 20 KB
    __shared__ unsigned short Vt[32 * VTP];       // 16.5 KB
    __shared__ unsigned short Pb[4][32 * PBP];    // 10 KB
    __shared__ float maskb[256];
    const int i = blockIdx.x, h = blockIdx.y, qh = blockIdx.z;
    const int tid = threadIdx.x;
    const int w = tid >> 6, L = tid & 63, lh = L >> 5, lc = L & 31;
    const long base = ((long)i * NH + h) * NJ * NCH;

    // stage K (row-major, padded)
#pragma unroll
    for (int it = 0; it < 4; ++it) {
        const int idx = it * 256 + tid;
        const int key = idx >> 2, c8 = (idx & 3) * 8;
        *(bf16x8*)&Ks[key * KSP + c8] = *(const bf16x8*)(k + base + key * NCH + c8);
    }
    // stage V transposed: Vt[ch][key]
    {
        const int key = tid;
        const u16x8 r0 = *(const u16x8*)(v + base + key * NCH);
        const u16x8 r1 = *(const u16x8*)(v + base + key * NCH + 8);
        const u16x8 r2 = *(const u16x8*)(v + base + key * NCH + 16);
        const u16x8 r3 = *(const u16x8*)(v + base + key * NCH + 24);
#pragma unroll
        for (int u = 0; u < 8; ++u) {
            Vt[(u)      * VTP + key] = r0[u];
            Vt[(u + 8)  * VTP + key] = r1[u];
            Vt[(u + 16) * VTP + key] = r2[u];
            Vt[(u + 24) * VTP + key] = r3[u];
        }
    }
    maskb[tid] = 1.0e9f * (mask[i * NJ + tid] - 1.0f);
    __syncthreads();

    const int qbase = qh * 128 + w * 32;

    // ---- S = Q @ K^T (+ bias) ----
    const bf16x8 a0 = *(const bf16x8*)(q + base + (qbase + lc) * NCH + lh * 8);
    const bf16x8 a1 = *(const bf16x8*)(q + base + (qbase + lc) * NCH + 16 + lh * 8);
    f32x16 S[8];
#pragma unroll
    for (int t = 0; t < 8; ++t) {
        bf16x8 b0 = *(const bf16x8*)&Ks[(t * 32 + lc) * KSP + lh * 8];
        bf16x8 b1 = *(const bf16x8*)&Ks[(t * 32 + lc) * KSP + 16 + lh * 8];
        f32x16 s = fzero16();
        s = mfma16(a0, b0, s);
        s = mfma16(a1, b1, s);
        S[t] = s;
    }

    // bias: tri[h][qrow][key] + mask bias
    int rowl[16];
#pragma unroll
    for (int r = 0; r < 16; ++r) rowl[r] = (r & 3) + 8 * (r >> 2) + 4 * lh;
#pragma unroll
    for (int t = 0; t < 8; ++t) {
        const float mb = maskb[t * 32 + lc];
        const float* trow = tri + ((long)h * NI) * NJ + t * 32 + lc;
#pragma unroll
        for (int r = 0; r < 16; ++r) {
            S[t][r] += mb + trow[(long)(qbase + rowl[r]) * NJ];
        }
    }

    // ---- softmax stats (row over 256 keys) ----
    float rm[16], ls[16];
#pragma unroll
    for (int r = 0; r < 16; ++r) {
        float m = S[0][r];
#pragma unroll
        for (int t = 1; t < 8; ++t) m = fmaxf(m, S[t][r]);
        rm[r] = m;
    }
#pragma unroll
    for (int d = 1; d < 32; d <<= 1)
#pragma unroll
        for (int r = 0; r < 16; ++r) rm[r] = fmaxf(rm[r], __shfl_xor(rm[r], d, 64));
#pragma unroll
    for (int r = 0; r < 16; ++r) ls[r] = 0.f;
#pragma unroll
    for (int t = 0; t < 8; ++t)
#pragma unroll
        for (int r = 0; r < 16; ++r) {
            const float p = __expf(S[t][r] - rm[r]);
            S[t][r] = p;
            ls[r] += p;
        }
#pragma unroll
    for (int d = 1; d < 32; d <<= 1)
#pragma unroll
        for (int r = 0; r < 16; ++r) ls[r] += __shfl_xor(ls[r], d, 64);

    // ---- O = P @ V  (P C-layout -> LDS -> A-layout) ----
    f32x16 O = fzero16();
    unsigned short* Pw = &Pb[w][0];
#pragma unroll
    for (int t = 0; t < 8; ++t) {
#pragma unroll
        for (int r = 0; r < 16; ++r)
            Pw[rowl[r] * PBP + lc] = f2bf(S[t][r]);
        bf16x8 pa0 = *(const bf16x8*)&Pw[lc * PBP + lh * 8];
        bf16x8 pa1 = *(const bf16x8*)&Pw[lc * PBP + 16 + lh * 8];
        bf16x8 vb0 = *(const bf16x8*)&Vt[lc * VTP + t * 32 + lh * 8];
        bf16x8 vb1 = *(const bf16x8*)&Vt[lc * VTP + t * 32 + 16 + lh * 8];
        O = mfma16(pa0, vb0, O);
        O = mfma16(pa1, vb1, O);
    }

    // ---- epilogue: normalize, gate, store og bf16 [tok][128] ----
#pragma unroll
    for (int r = 0; r < 16; ++r) {
        const int qrow = qbase + rowl[r];
        const float ov = O[r] / ls[r];
        const float gv = bf2f(g[base + (long)qrow * NCH + lc]);
        og[((long)i * NJ + qrow) * NC + h * NCH + lc] = f2bf(ov * gv);
    }
}

// ---------------------------------------------------------------------------
// Kernel 3: out = og @ wo + bo  (MFMA). Block = 64 tokens, wave w = cols w*32..
// ---------------------------------------------------------------------------
#define OGP 136
__global__ __launch_bounds__(256, 4) void out_proj_mfma(
    const unsigned short* __restrict__ og, const unsigned short* __restrict__ Wto,
    const float* __restrict__ bo, float* __restrict__ out)
{
    __shared__ unsigned short t_og[64 * OGP];
    const int tid = threadIdx.x;
    const long tok0 = (long)blockIdx.x * 64;
#pragma unroll
    for (int it = 0; it < 4; ++it) {
        const int idx = it * 256 + tid;
        const int tk = idx >> 4, c8 = (idx & 15) * 8;
        *(bf16x8*)&t_og[tk * OGP + c8] = *(const bf16x8*)(og + (tok0 + tk) * NC + c8);
    }
    __syncthreads();

    const int w = tid >> 6, L = tid & 63, lh = L >> 5, lc = L & 31;
    f32x16 acc[2];
    acc[0] = fzero16(); acc[1] = fzero16();
#pragma unroll
    for (int k0 = 0; k0 < 8; ++k0) {
        bf16x8 a0 = *(const bf16x8*)&t_og[(lc)      * OGP + k0 * 16 + lh * 8];
        bf16x8 a1 = *(const bf16x8*)&t_og[(32 + lc) * OGP + k0 * 16 + lh * 8];
        bf16x8 b  = *(const bf16x8*)&Wto[(w * 32 + lc) * 128 + k0 * 16 + lh * 8];
        acc[0] = mfma16(a0, b, acc[0]);
        acc[1] = mfma16(a1, b, acc[1]);
    }
    const float bov = bo[w * 32 + lc];
#pragma unroll
    for (int mt = 0; mt < 2; ++mt)
#pragma unroll
        for (int r = 0; r < 16; ++r) {
            const int row = mt * 32 + (r & 3) + 8 * (r >> 2) + 4 * lh;
            out[(tok0 + row) * NC + w * 32 + lc] = acc[mt][r] + bov;
        }
}

// ---------------------------------------------------------------------------
extern "C" void kernel_launch(void* const* d_in, const int* in_sizes, int n_in,
                              void* d_out, int out_size, void* d_ws, size_t ws_size,
                              hipStream_t stream) {
    const float* x     = (const float*)d_in[0];
    const float* mask  = (const float*)d_in[1];
    const float* ln_w  = (const float*)d_in[3];
    const float* ln_b  = (const float*)d_in[4];
    const float* w_tri = (const float*)d_in[5];
    const float* wq    = (const float*)d_in[6];
    const float* wk    = (const float*)d_in[7];
    const float* wv    = (const float*)d_in[8];
    const float* wg    = (const float*)d_in[9];
    const float* bg    = (const float*)d_in[10];
    const float* wo    = (const float*)d_in[11];
    const float* bo    = (const float*)d_in[12];
    float* out = (float*)d_out;

    char* p = (char*)d_ws;
    const long TOK = (long)NI * NJ;                     // 65536
    const long QB  = TOK * NC * sizeof(unsigned short); // 16.78 MB
    unsigned short* q  = (unsigned short*)p; p += QB;
    unsigned short* k  = (unsigned short*)p; p += QB;
    unsigned short* v  = (unsigned short*)p; p += QB;
    unsigned short* g  = (unsigned short*)p; p += QB;
    unsigned short* og = (unsigned short*)p; p += QB;
    float* tri = (float*)p;          p += (long)NH * NI * NJ * sizeof(float);
    unsigned short* Wt_all = (unsigned short*)p; p += 4 * 128 * 128 * sizeof(unsigned short);
    unsigned short* Wto    = (unsigned short*)p; p += 128 * 128 * sizeof(unsigned short);

    hipLaunchKernelGGL(convert_weights, dim3(320), dim3(256), 0, stream,
                       wq, wk, wv, wg, wo, Wt_all, Wto);
    hipLaunchKernelGGL(ln_proj_mfma, dim3(TOK / 64), dim3(256), 0, stream,
                       x, ln_w, ln_b, w_tri, Wt_all, bg, q, k, v, g, tri);
    hipLaunchKernelGGL(attn_mfma, dim3(NI, NH, 2), dim3(256), 0, stream,
                       q, k, v, g, tri, mask, og);
    hipLaunchKernelGGL(out_proj_mfma, dim3(TOK / 64), dim3(256), 0, stream,
                       og, Wto, bo, out);
}